// Round 1
// baseline (598.574 us; speedup 1.0000x reference)
//
#include <hip/hip_runtime.h>

// Problem constants (from reference):
// B=16384, F=45, V=10000, D=256, H=32
// Key insight: the MLP is LINEAR (no activation), so
//   out[b] = sum_f tables[f, src[b,f]] . (W1@W2)  +  F*(b1@W2 + b2)
// Precompute w = W1@W2 [D], c = b1@W2+b2 (scalar), then per-row dot
// t[f,v] = tables[f,v,:].w  (450k floats), then gather-sum over src.

#define BN 16384
#define FN 45
#define VN 10000
#define DN 256
#define HN 32

// ---------------- Kernel A: w = W1 @ W2, c = b1@W2 + b2 ----------------
__global__ void prep_w_kernel(const float* __restrict__ W1,
                              const float* __restrict__ b1,
                              const float* __restrict__ W2,
                              const float* __restrict__ b2,
                              float* __restrict__ w_out,
                              float* __restrict__ c_out) {
    int d = threadIdx.x;  // 0..255
    float s = 0.f;
#pragma unroll
    for (int h = 0; h < HN; ++h) s += W1[d * HN + h] * W2[h];
    w_out[d] = s;
    if (d == 0) {
        float cc = 0.f;
#pragma unroll
        for (int h = 0; h < HN; ++h) cc += b1[h] * W2[h];
        c_out[0] = cc + b2[0];
    }
}

// ---------------- Kernel B: t[r] = tables[r*256 .. +255] . w ----------------
// One wave per row: 64 lanes x float4 = 256 floats = exactly one row.
// Grid-stride over R = F*V = 450000 rows. Memory-bound: streams 460.8 MB.
__global__ __launch_bounds__(256, 8)
void row_dot_kernel(const float* __restrict__ tables,
                    const float* __restrict__ w,
                    float* __restrict__ t,
                    int R) {
    const int lane = threadIdx.x & 63;
    const int wave_in_block = threadIdx.x >> 6;
    const int waves_per_block = blockDim.x >> 6;
    const int nwaves = gridDim.x * waves_per_block;
    int wave = blockIdx.x * waves_per_block + wave_in_block;

    // Each lane's 4 weights (w is 256 floats = 64 float4)
    const float4 wv = reinterpret_cast<const float4*>(w)[lane];

    for (int r = wave; r < R; r += nwaves) {
        const float4 v =
            reinterpret_cast<const float4*>(tables + (size_t)r * DN)[lane];
        float s = v.x * wv.x + v.y * wv.y + v.z * wv.z + v.w * wv.w;
        // wave-64 butterfly reduce
#pragma unroll
        for (int m = 1; m < 64; m <<= 1) s += __shfl_xor(s, m);
        if (lane == 0) t[r] = s;
    }
}

// ---------------- Kernel C: out[b] = sum_f t[f, src[b,f]] + F*c ----------------
// One wave per output row b; lane f (<45) reads src[b,f], gathers t.
__global__ __launch_bounds__(256)
void gather_sum_kernel(const int* __restrict__ src,
                       const float* __restrict__ t,
                       const float* __restrict__ c,
                       float* __restrict__ out) {
    const int lane = threadIdx.x & 63;
    const int wave = blockIdx.x * (blockDim.x >> 6) + (threadIdx.x >> 6);
    if (wave >= BN) return;

    float s = 0.f;
    if (lane < FN) {
        const int idx = src[wave * FN + lane];
        s = t[lane * VN + idx];
    }
#pragma unroll
    for (int m = 1; m < 64; m <<= 1) s += __shfl_xor(s, m);
    if (lane == 0) out[wave] = s + (float)FN * c[0];
}

extern "C" void kernel_launch(void* const* d_in, const int* in_sizes, int n_in,
                              void* d_out, int out_size, void* d_ws, size_t ws_size,
                              hipStream_t stream) {
    const int* src = (const int*)d_in[0];
    const float* tables = (const float*)d_in[1];
    const float* W1 = (const float*)d_in[2];
    const float* b1 = (const float*)d_in[3];
    const float* W2 = (const float*)d_in[4];
    const float* b2 = (const float*)d_in[5];
    float* out = (float*)d_out;

    // Workspace layout (floats): [0..255]=w, [256]=c, [512..512+450000)=t
    float* ws = (float*)d_ws;
    float* w = ws;
    float* c = ws + 256;
    float* t = ws + 512;
    const int R = FN * VN;  // 450000

    prep_w_kernel<<<1, 256, 0, stream>>>(W1, b1, W2, b2, w, c);

    // 2048 blocks * 4 waves = 8192 waves = 32 waves/CU on 256 CUs
    row_dot_kernel<<<2048, 256, 0, stream>>>(tables, w, t, R);

    // 16384 waves = 4096 blocks of 4 waves
    gather_sum_kernel<<<4096, 256, 0, stream>>>(src, t, c, out);
}